// Round 2
// baseline (716.998 us; speedup 1.0000x reference)
//
#include <hip/hip_runtime.h>
#include <cstdint>
#include <cstddef>

typedef unsigned short u16;
typedef __bf16 bf16_t;
typedef bf16_t bf16x8 __attribute__((ext_vector_type(8)));
typedef float f32x4 __attribute__((ext_vector_type(4)));

#define DEV __device__ __forceinline__

DEV u16 f2bf(float f) {
  unsigned u = __float_as_uint(f);
  u += 0x7fffu + ((u >> 16) & 1u);
  return (u16)(u >> 16);
}
DEV float bf2f(u16 h) {
  return __uint_as_float(((unsigned)h) << 16);
}

// ---------------------------------------------------------------- converts
__global__ __launch_bounds__(256)
void convert_f32_bf16(const float* __restrict__ s, u16* __restrict__ d, long n) {
  for (long i = (long)blockIdx.x * 256 + threadIdx.x; i * 4 < n;
       i += (long)gridDim.x * 256) {
    float4 v = *(const float4*)(s + i * 4);
    ushort4 o;
    o.x = f2bf(v.x); o.y = f2bf(v.y); o.z = f2bf(v.z); o.w = f2bf(v.w);
    *(ushort4*)(d + i * 4) = o;
  }
}

// Acat = [queries | image_tokens] as bf16, 16384 x 2048
__global__ __launch_bounds__(256)
void build_acat(const float* __restrict__ q, const float* __restrict__ it,
                u16* __restrict__ dst) {
  const long total = 16384l * 2048 / 4;
  for (long i = (long)blockIdx.x * 256 + threadIdx.x; i < total;
       i += (long)gridDim.x * 256) {
    long e = i * 4;
    int m = (int)(e >> 11);
    int k = (int)(e & 2047);
    const float* s = (k < 1024) ? (q + (long)m * 1024 + k)
                                : (it + (long)m * 1024 + (k - 1024));
    float4 v = *(const float4*)s;
    ushort4 o;
    o.x = f2bf(v.x); o.y = f2bf(v.y); o.z = f2bf(v.z); o.w = f2bf(v.w);
    *(ushort4*)(dst + e) = o;
  }
}

// ---------------------------------------------------------------- layernorm
__global__ __launch_bounds__(256)
void ln_rows(const float* __restrict__ x, const float* __restrict__ g,
             const float* __restrict__ b, u16* __restrict__ out) {
  __shared__ float red[8];
  const int row = blockIdx.x, tid = threadIdx.x;
  const float* xr = x + (size_t)row * 1024;
  float4 v = *(const float4*)(xr + tid * 4);
  float s = v.x + v.y + v.z + v.w;
  float ss = v.x * v.x + v.y * v.y + v.z * v.z + v.w * v.w;
#pragma unroll
  for (int o = 32; o > 0; o >>= 1) { s += __shfl_xor(s, o); ss += __shfl_xor(ss, o); }
  if ((tid & 63) == 0) { red[tid >> 6] = s; red[4 + (tid >> 6)] = ss; }
  __syncthreads();
  s = red[0] + red[1] + red[2] + red[3];
  ss = red[4] + red[5] + red[6] + red[7];
  const float mean = s * 0.0009765625f;
  const float var = ss * 0.0009765625f - mean * mean;
  const float rinv = rsqrtf(var + 1e-5f);
  const int c = tid * 4;
  float4 gg = *(const float4*)(g + c);
  float4 bb = *(const float4*)(b + c);
  ushort4 o4;
  o4.x = f2bf((v.x - mean) * rinv * gg.x + bb.x);
  o4.y = f2bf((v.y - mean) * rinv * gg.y + bb.y);
  o4.z = f2bf((v.z - mean) * rinv * gg.z + bb.z);
  o4.w = f2bf((v.w - mean) * rinv * gg.w + bb.w);
  *(ushort4*)(out + (size_t)row * 1024 + c) = o4;
}

// K/V layernorm with the window gather folded in.
// out row m (m = (b*16+qw)*36 + w) reads winp row (b*576 + g(qw,w))
__global__ __launch_bounds__(256)
void ln_kv(const float* __restrict__ winp,
           const float* __restrict__ gk, const float* __restrict__ bk,
           const float* __restrict__ gv, const float* __restrict__ bv,
           u16* __restrict__ kout, u16* __restrict__ vout) {
  __shared__ float red[8];
  const int m = blockIdx.x, tid = threadIdx.x;
  const int b = m / 576, rem = m % 576;
  const int qw = rem / 36, w = rem % 36;
  const int gidx = (qw >> 2) * 144 + (w / 6) * 24 + (qw & 3) * 6 + (w % 6);
  const float* xr = winp + ((size_t)b * 576 + gidx) * 1024;
  float4 v = *(const float4*)(xr + tid * 4);
  float s = v.x + v.y + v.z + v.w;
  float ss = v.x * v.x + v.y * v.y + v.z * v.z + v.w * v.w;
#pragma unroll
  for (int o = 32; o > 0; o >>= 1) { s += __shfl_xor(s, o); ss += __shfl_xor(ss, o); }
  if ((tid & 63) == 0) { red[tid >> 6] = s; red[4 + (tid >> 6)] = ss; }
  __syncthreads();
  s = red[0] + red[1] + red[2] + red[3];
  ss = red[4] + red[5] + red[6] + red[7];
  const float mean = s * 0.0009765625f;
  const float var = ss * 0.0009765625f - mean * mean;
  const float rinv = rsqrtf(var + 1e-5f);
  const int c = tid * 4;
  float4 gg = *(const float4*)(gk + c);
  float4 bb = *(const float4*)(bk + c);
  float4 g2 = *(const float4*)(gv + c);
  float4 b2 = *(const float4*)(bv + c);
  float nx = (v.x - mean) * rinv, ny = (v.y - mean) * rinv;
  float nz = (v.z - mean) * rinv, nw = (v.w - mean) * rinv;
  ushort4 ok, ov;
  ok.x = f2bf(nx * gg.x + bb.x); ok.y = f2bf(ny * gg.y + bb.y);
  ok.z = f2bf(nz * gg.z + bb.z); ok.w = f2bf(nw * gg.w + bb.w);
  ov.x = f2bf(nx * g2.x + b2.x); ov.y = f2bf(ny * g2.y + b2.y);
  ov.z = f2bf(nz * g2.z + b2.z); ov.w = f2bf(nw * g2.w + b2.w);
  *(ushort4*)(kout + (size_t)m * 1024 + c) = ok;
  *(ushort4*)(vout + (size_t)m * 1024 + c) = ov;
}

// ---------------------------------------------------------------- GEMM
// C[M,N] = A[M,K] * B[N,K]^T   (A,B bf16 row-major; acc fp32)
// EPI: 0 = bf16 store, 1 = f32 store, 2 = f32 store of acc+addF, 3 = gelu->bf16
template <int EPI>
__global__ __launch_bounds__(256)
void gemm_bt(const u16* __restrict__ A, const u16* __restrict__ Bw,
             u16* __restrict__ outB, float* __restrict__ outF,
             const float* __restrict__ addF, int M, int N, int K) {
  __shared__ __align__(16) u16 As[128 * 64];
  __shared__ __align__(16) u16 Bs[128 * 64];
  const int tid = threadIdx.x;
  const int wave = tid >> 6, lane = tid & 63;
  const int brow = blockIdx.x * 128, bcol = blockIdx.y * 128;
  const int wr = (wave >> 1) * 64, wc = (wave & 1) * 64;
  const int fr = lane & 15, fq = lane >> 4;
  const int srow = lane >> 3;        // 0..7 within an 8-row group
  const int scol = (lane & 7) * 8;   // k element offset (16B chunks)
  f32x4 acc[4][4];
#pragma unroll
  for (int m = 0; m < 4; ++m)
#pragma unroll
    for (int n = 0; n < 4; ++n) acc[m][n] = (f32x4){0.f, 0.f, 0.f, 0.f};

  for (int k0 = 0; k0 < K; k0 += 64) {
#pragma unroll
    for (int t = 0; t < 4; ++t) {
      const int j = wave * 4 + t;                  // 16 chunks of 8 rows
      const u16* ga = A + (size_t)(brow + j * 8 + srow) * K + (k0 + scol);
      const u16* gb = Bw + (size_t)(bcol + j * 8 + srow) * K + (k0 + scol);
      __builtin_amdgcn_global_load_lds(
          (const __attribute__((address_space(1))) void*)ga,
          (__attribute__((address_space(3))) void*)&As[j * 512], 16, 0, 0);
      __builtin_amdgcn_global_load_lds(
          (const __attribute__((address_space(1))) void*)gb,
          (__attribute__((address_space(3))) void*)&Bs[j * 512], 16, 0, 0);
    }
    __syncthreads();
#pragma unroll
    for (int kk = 0; kk < 2; ++kk) {
      bf16x8 af[4], bfv[4];
#pragma unroll
      for (int m = 0; m < 4; ++m)
        af[m] = *(const bf16x8*)&As[(wr + m * 16 + fr) * 64 + kk * 32 + fq * 8];
#pragma unroll
      for (int n = 0; n < 4; ++n)
        bfv[n] = *(const bf16x8*)&Bs[(wc + n * 16 + fr) * 64 + kk * 32 + fq * 8];
#pragma unroll
      for (int m = 0; m < 4; ++m)
#pragma unroll
        for (int n = 0; n < 4; ++n)
          acc[m][n] = __builtin_amdgcn_mfma_f32_16x16x32_bf16(af[m], bfv[n],
                                                              acc[m][n], 0, 0, 0);
    }
    __syncthreads();
  }

#pragma unroll
  for (int m = 0; m < 4; ++m) {
    const int row0 = brow + wr + m * 16 + fq * 4;
#pragma unroll
    for (int n = 0; n < 4; ++n) {
      const int col = bcol + wc + n * 16 + fr;
#pragma unroll
      for (int j = 0; j < 4; ++j) {
        const size_t o = (size_t)(row0 + j) * N + col;
        const float vv = acc[m][n][j];
        if constexpr (EPI == 0) {
          outB[o] = f2bf(vv);
        } else if constexpr (EPI == 1) {
          outF[o] = vv;
        } else if constexpr (EPI == 2) {
          outF[o] = vv + addF[o];
        } else {
          outB[o] = f2bf(0.5f * vv * (1.0f + erff(vv * 0.70710678118654752f)));
        }
      }
    }
  }
}

// ---------------------------------------------------------------- attention
// One block per (b, qw, h): Q 64x64, K/V 36x64, softmax over 36.
__global__ __launch_bounds__(256)
void attn_kernel(const u16* __restrict__ q, const u16* __restrict__ k,
                 const u16* __restrict__ v, u16* __restrict__ ao) {
  __shared__ __align__(16) u16 Qs[64 * 64];
  __shared__ __align__(16) u16 Ks[36 * 64];
  __shared__ __align__(16) u16 Vs[36 * 64];
  __shared__ float Ps[64 * 36];
  const int bid = blockIdx.x;
  const int h = bid & 15, qw = (bid >> 4) & 15, b = bid >> 8;
  const int tid = threadIdx.x;
  const size_t qbase = ((size_t)b * 1024) * 1024 + (size_t)h * 64;
  for (int i = tid; i < 64 * 16; i += 256) {
    int l = i >> 4, d4 = (i & 15) * 4;
    *(ushort4*)&Qs[l * 64 + d4] =
        *(const ushort4*)&q[qbase + (size_t)(l * 16 + qw) * 1024 + d4];
  }
  const size_t kvbase = ((size_t)(b * 16 + qw)) * 36 * 1024 + (size_t)h * 64;
  for (int i = tid; i < 36 * 16; i += 256) {
    int w = i >> 4, d4 = (i & 15) * 4;
    *(ushort4*)&Ks[w * 64 + d4] = *(const ushort4*)&k[kvbase + (size_t)w * 1024 + d4];
    *(ushort4*)&Vs[w * 64 + d4] = *(const ushort4*)&v[kvbase + (size_t)w * 1024 + d4];
  }
  __syncthreads();
  const int l = tid >> 2, quad = tid & 3;
  float sc[9];
#pragma unroll
  for (int wi = 0; wi < 9; ++wi) {
    int w = quad * 9 + wi;
    float acc = 0.f;
#pragma unroll
    for (int dd = 0; dd < 64; dd += 4) {
      ushort4 qv = *(const ushort4*)&Qs[l * 64 + dd];
      ushort4 kv = *(const ushort4*)&Ks[w * 64 + dd];
      acc += bf2f(qv.x) * bf2f(kv.x) + bf2f(qv.y) * bf2f(kv.y) +
             bf2f(qv.z) * bf2f(kv.z) + bf2f(qv.w) * bf2f(kv.w);
    }
    sc[wi] = acc * 0.125f;
  }
  float mx = sc[0];
#pragma unroll
  for (int wi = 1; wi < 9; ++wi) mx = fmaxf(mx, sc[wi]);
  mx = fmaxf(mx, __shfl_xor(mx, 1));
  mx = fmaxf(mx, __shfl_xor(mx, 2));
  float sum = 0.f;
#pragma unroll
  for (int wi = 0; wi < 9; ++wi) { sc[wi] = __expf(sc[wi] - mx); sum += sc[wi]; }
  sum += __shfl_xor(sum, 1);
  sum += __shfl_xor(sum, 2);
  const float inv = 1.0f / sum;
#pragma unroll
  for (int wi = 0; wi < 9; ++wi) Ps[l * 36 + quad * 9 + wi] = sc[wi] * inv;
  __syncthreads();
  float o[16];
#pragma unroll
  for (int dd = 0; dd < 16; ++dd) o[dd] = 0.f;
  for (int w = 0; w < 36; ++w) {
    float p = Ps[l * 36 + w];
#pragma unroll
    for (int dd = 0; dd < 16; dd += 4) {
      ushort4 vv = *(const ushort4*)&Vs[w * 64 + quad * 16 + dd];
      o[dd] += p * bf2f(vv.x); o[dd + 1] += p * bf2f(vv.y);
      o[dd + 2] += p * bf2f(vv.z); o[dd + 3] += p * bf2f(vv.w);
    }
  }
  const size_t obase = qbase + (size_t)(l * 16 + qw) * 1024 + quad * 16;
#pragma unroll
  for (int dd = 0; dd < 16; dd += 4) {
    ushort4 ov;
    ov.x = f2bf(o[dd]); ov.y = f2bf(o[dd + 1]);
    ov.z = f2bf(o[dd + 2]); ov.w = f2bf(o[dd + 3]);
    *(ushort4*)&ao[obase + dd] = ov;
  }
}

// ---------------------------------------------------------------- launch
extern "C" void kernel_launch(void* const* d_in, const int* in_sizes, int n_in,
                              void* d_out, int out_size, void* d_ws, size_t ws_size,
                              hipStream_t stream) {
  const float* gctx = (const float*)d_in[1];
  const float* queries = (const float*)d_in[4];
  const float* image_tokens = (const float*)d_in[5];
  const float* W_in = (const float*)d_in[7];
  const float* W_ctx = (const float*)d_in[8];
  const float* ln_q_g = (const float*)d_in[9];
  const float* ln_q_b = (const float*)d_in[10];
  const float* Wq = (const float*)d_in[11];
  const float* ln_k_g = (const float*)d_in[12];
  const float* ln_k_b = (const float*)d_in[13];
  const float* Wk = (const float*)d_in[14];
  const float* ln_v_g = (const float*)d_in[15];
  const float* ln_v_b = (const float*)d_in[16];
  const float* Wv = (const float*)d_in[17];
  const float* Wo = (const float*)d_in[18];
  const float* norm_g = (const float*)d_in[19];
  const float* norm_b = (const float*)d_in[20];
  const float* W1 = (const float*)d_in[21];
  const float* W2 = (const float*)d_in[22];
  float* out = (float*)d_out;

  // ---- tight workspace arena: 136 MiB total ----
  // W region: weights bf16 (18 MiB, live whole call)
  // A region: 64 MiB  acat -> {pqln | qmat} -> {vln | aoh} -> xmat
  // B region: 36 MiB  winp(f32) -> {kmat | vmat} -> gelu_out
  // C region: 18 MiB  gcb -> kln
  // pq lives in d_out (f32, 64 MiB): written by GEMM1 before any read.
  char* ws = (char*)d_ws;
  const size_t MB = 1024 * 1024;
  u16* w_in_b  = (u16*)(ws + 0 * MB);    // 4 MiB
  u16* w_ctx_b = (u16*)(ws + 4 * MB);
  u16* wq_b    = (u16*)(ws + 6 * MB);
  u16* wk_b    = (u16*)(ws + 8 * MB);
  u16* wv_b    = (u16*)(ws + 10 * MB);
  u16* wo_b    = (u16*)(ws + 12 * MB);
  u16* w1_b    = (u16*)(ws + 14 * MB);
  u16* w2_b    = (u16*)(ws + 16 * MB);
  char* regA = ws + 18 * MB;   // 64 MiB
  char* regB = regA + 64 * MB; // 36 MiB
  char* regC = regB + 36 * MB; // 18 MiB
  // total = 18 + 64 + 36 + 18 = 136 MiB

  u16* acat = (u16*)regA;               // 16384 x 2048 bf16 (stages 2-3)
  u16* pqln = (u16*)regA;               // 16384 x 1024 bf16 (4-5), acat dead
  u16* qmat = (u16*)(regA + 32 * MB);   // 16384 x 1024 bf16 (5-11)
  u16* vln  = (u16*)regA;               // 9216 x 1024 bf16 (8-10), pqln dead
  u16* aoh  = (u16*)regA;               // 16384 x 1024 bf16 (11-12), vln dead
  u16* xmat = (u16*)(regA + 32 * MB);   // 16384 x 1024 bf16 (13-14), qmat dead

  float* winp = (float*)regB;           // 9216 x 1024 f32 (7-8)
  u16* kmat = (u16*)regB;               // 9216 x 1024 bf16 (9-11), winp dead
  u16* vmat = (u16*)(regB + 18 * MB);   // 9216 x 1024 bf16 (10-11)
  u16* gout = (u16*)regB;               // 16384 x 1024 bf16 (14-15), kmat/vmat dead

  u16* gcb = (u16*)regC;                // 9216 x 1024 bf16 (6-7)
  u16* kln = (u16*)regC;                // 9216 x 1024 bf16 (8-9), gcb dead

  float* pq = out;                      // f32 16384 x 1024, in d_out

  auto cvt = [&](const float* s, u16* d, long n) {
    long bn = (n / 4 + 255) / 256;
    if (bn > 4096) bn = 4096;
    convert_f32_bf16<<<dim3((unsigned)bn), dim3(256), 0, stream>>>(s, d, n);
  };
  cvt(W_in, w_in_b, 2048l * 1024);
  cvt(W_ctx, w_ctx_b, 1024l * 1024);
  cvt(Wq, wq_b, 1024l * 1024);
  cvt(Wk, wk_b, 1024l * 1024);
  cvt(Wv, wv_b, 1024l * 1024);
  cvt(Wo, wo_b, 1024l * 1024);
  cvt(W1, w1_b, 1024l * 1024);
  cvt(W2, w2_b, 1024l * 1024);
  cvt(gctx, gcb, 9216l * 1024);
  build_acat<<<dim3(8192), dim3(256), 0, stream>>>(queries, image_tokens, acat);

  // 3: pq = Acat @ W_in^T  (fp32 -> d_out)
  gemm_bt<1><<<dim3(128, 8), dim3(256), 0, stream>>>(acat, w_in_b, nullptr, pq,
                                                     nullptr, 16384, 1024, 2048);
  // 4: ln_q(pq) -> bf16
  ln_rows<<<dim3(16384), dim3(256), 0, stream>>>(pq, ln_q_g, ln_q_b, pqln);
  // 5: q = ln(pq) @ Wq^T  (bf16)
  gemm_bt<0><<<dim3(128, 8), dim3(256), 0, stream>>>(pqln, wq_b, qmat, nullptr,
                                                     nullptr, 16384, 1024, 1024);
  // 7: winp = gctx_bf @ W_ctx^T  (fp32)
  gemm_bt<1><<<dim3(72, 8), dim3(256), 0, stream>>>(gcb, w_ctx_b, nullptr, winp,
                                                    nullptr, 9216, 1024, 1024);
  // 8: gather + ln_k / ln_v -> bf16
  ln_kv<<<dim3(9216), dim3(256), 0, stream>>>(winp, ln_k_g, ln_k_b, ln_v_g,
                                              ln_v_b, kln, vln);
  // 9,10: k/v projections
  gemm_bt<0><<<dim3(72, 8), dim3(256), 0, stream>>>(kln, wk_b, kmat, nullptr,
                                                    nullptr, 9216, 1024, 1024);
  gemm_bt<0><<<dim3(72, 8), dim3(256), 0, stream>>>(vln, wv_b, vmat, nullptr,
                                                    nullptr, 9216, 1024, 1024);
  // 11: attention
  attn_kernel<<<dim3(4096), dim3(256), 0, stream>>>(qmat, kmat, vmat, aoh);
  // 12: y = ao @ Wo^T + pq  (fp32, in-place in d_out)
  gemm_bt<2><<<dim3(128, 8), dim3(256), 0, stream>>>(aoh, wo_b, nullptr, pq, pq,
                                                     16384, 1024, 1024);
  // 13: x = ln(y) -> bf16
  ln_rows<<<dim3(16384), dim3(256), 0, stream>>>(pq, norm_g, norm_b, xmat);
  // 14: h = gelu(x @ W1^T) -> bf16
  gemm_bt<3><<<dim3(128, 8), dim3(256), 0, stream>>>(xmat, w1_b, gout, nullptr,
                                                     nullptr, 16384, 1024, 1024);
  // 15: out = h @ W2^T + image_tokens  (fp32 -> d_out)
  gemm_bt<2><<<dim3(128, 8), dim3(256), 0, stream>>>(gout, w2_b, nullptr, out,
                                                     image_tokens, 16384, 1024, 1024);
}

// Round 3
// 673.982 us; speedup vs baseline: 1.0638x; 1.0638x over previous
//
#include <hip/hip_runtime.h>
#include <cstdint>
#include <cstddef>

typedef unsigned short u16;
typedef __bf16 bf16_t;
typedef bf16_t bf16x8 __attribute__((ext_vector_type(8)));
typedef float f32x4 __attribute__((ext_vector_type(4)));

#define DEV __device__ __forceinline__

DEV u16 f2bf(float f) {
  unsigned u = __float_as_uint(f);
  u += 0x7fffu + ((u >> 16) & 1u);
  return (u16)(u >> 16);
}
DEV float bf2f(u16 h) {
  return __uint_as_float(((unsigned)h) << 16);
}

// ---------------------------------------------------------------- converts
// One batched kernel for all plain f32->bf16 conversions (8 weights + gctx).
struct Cvt9 {
  const float* s[9];
  u16* d[9];
  long cumv[10];  // cumulative vec4 counts
};

__global__ __launch_bounds__(256)
void convert_batch(Cvt9 jobs) {
  const long total = jobs.cumv[9];
  for (long i = (long)blockIdx.x * 256 + threadIdx.x; i < total;
       i += (long)gridDim.x * 256) {
    int j = 0;
#pragma unroll
    for (int t = 0; t < 8; ++t)
      if (i >= jobs.cumv[t + 1]) j = t + 1;
    const long e = (i - jobs.cumv[j]) * 4;
    float4 v = *(const float4*)(jobs.s[j] + e);
    ushort4 o;
    o.x = f2bf(v.x); o.y = f2bf(v.y); o.z = f2bf(v.z); o.w = f2bf(v.w);
    *(ushort4*)(jobs.d[j] + e) = o;
  }
}

// Acat = [queries | image_tokens] as bf16, 16384 x 2048
__global__ __launch_bounds__(256)
void build_acat(const float* __restrict__ q, const float* __restrict__ it,
                u16* __restrict__ dst) {
  const long total = 16384l * 2048 / 4;
  for (long i = (long)blockIdx.x * 256 + threadIdx.x; i < total;
       i += (long)gridDim.x * 256) {
    long e = i * 4;
    int m = (int)(e >> 11);
    int k = (int)(e & 2047);
    const float* s = (k < 1024) ? (q + (long)m * 1024 + k)
                                : (it + (long)m * 1024 + (k - 1024));
    float4 v = *(const float4*)s;
    ushort4 o;
    o.x = f2bf(v.x); o.y = f2bf(v.y); o.z = f2bf(v.z); o.w = f2bf(v.w);
    *(ushort4*)(dst + e) = o;
  }
}

// ---------------------------------------------------------------- layernorm
__global__ __launch_bounds__(256)
void ln_rows(const float* __restrict__ x, const float* __restrict__ g,
             const float* __restrict__ b, u16* __restrict__ out) {
  __shared__ float red[8];
  const int row = blockIdx.x, tid = threadIdx.x;
  const float* xr = x + (size_t)row * 1024;
  float4 v = *(const float4*)(xr + tid * 4);
  float s = v.x + v.y + v.z + v.w;
  float ss = v.x * v.x + v.y * v.y + v.z * v.z + v.w * v.w;
#pragma unroll
  for (int o = 32; o > 0; o >>= 1) { s += __shfl_xor(s, o); ss += __shfl_xor(ss, o); }
  if ((tid & 63) == 0) { red[tid >> 6] = s; red[4 + (tid >> 6)] = ss; }
  __syncthreads();
  s = red[0] + red[1] + red[2] + red[3];
  ss = red[4] + red[5] + red[6] + red[7];
  const float mean = s * 0.0009765625f;
  const float var = ss * 0.0009765625f - mean * mean;
  const float rinv = rsqrtf(var + 1e-5f);
  const int c = tid * 4;
  float4 gg = *(const float4*)(g + c);
  float4 bb = *(const float4*)(b + c);
  ushort4 o4;
  o4.x = f2bf((v.x - mean) * rinv * gg.x + bb.x);
  o4.y = f2bf((v.y - mean) * rinv * gg.y + bb.y);
  o4.z = f2bf((v.z - mean) * rinv * gg.z + bb.z);
  o4.w = f2bf((v.w - mean) * rinv * gg.w + bb.w);
  *(ushort4*)(out + (size_t)row * 1024 + c) = o4;
}

// K/V layernorm with the window gather folded in.
__global__ __launch_bounds__(256)
void ln_kv(const float* __restrict__ winp,
           const float* __restrict__ gk, const float* __restrict__ bk,
           const float* __restrict__ gv, const float* __restrict__ bv,
           u16* __restrict__ kout, u16* __restrict__ vout) {
  __shared__ float red[8];
  const int m = blockIdx.x, tid = threadIdx.x;
  const int b = m / 576, rem = m % 576;
  const int qw = rem / 36, w = rem % 36;
  const int gidx = (qw >> 2) * 144 + (w / 6) * 24 + (qw & 3) * 6 + (w % 6);
  const float* xr = winp + ((size_t)b * 576 + gidx) * 1024;
  float4 v = *(const float4*)(xr + tid * 4);
  float s = v.x + v.y + v.z + v.w;
  float ss = v.x * v.x + v.y * v.y + v.z * v.z + v.w * v.w;
#pragma unroll
  for (int o = 32; o > 0; o >>= 1) { s += __shfl_xor(s, o); ss += __shfl_xor(ss, o); }
  if ((tid & 63) == 0) { red[tid >> 6] = s; red[4 + (tid >> 6)] = ss; }
  __syncthreads();
  s = red[0] + red[1] + red[2] + red[3];
  ss = red[4] + red[5] + red[6] + red[7];
  const float mean = s * 0.0009765625f;
  const float var = ss * 0.0009765625f - mean * mean;
  const float rinv = rsqrtf(var + 1e-5f);
  const int c = tid * 4;
  float4 gg = *(const float4*)(gk + c);
  float4 bb = *(const float4*)(bk + c);
  float4 g2 = *(const float4*)(gv + c);
  float4 b2 = *(const float4*)(bv + c);
  float nx = (v.x - mean) * rinv, ny = (v.y - mean) * rinv;
  float nz = (v.z - mean) * rinv, nw = (v.w - mean) * rinv;
  ushort4 ok, ov;
  ok.x = f2bf(nx * gg.x + bb.x); ok.y = f2bf(ny * gg.y + bb.y);
  ok.z = f2bf(nz * gg.z + bb.z); ok.w = f2bf(nw * gg.w + bb.w);
  ov.x = f2bf(nx * g2.x + b2.x); ov.y = f2bf(ny * g2.y + b2.y);
  ov.z = f2bf(nz * g2.z + b2.z); ov.w = f2bf(nw * g2.w + b2.w);
  *(ushort4*)(kout + (size_t)m * 1024 + c) = ok;
  *(ushort4*)(vout + (size_t)m * 1024 + c) = ov;
}

// ---------------------------------------------------------------- GEMM
// C[M,N] = A[M,K] * B[N,K]^T  (bf16 in, fp32 acc), 128x128 tile, BK=64,
// double-buffered LDS, minimum-2-phase pipeline (stage t+1 before compute t,
// ONE barrier per K-step; __syncthreads provides the vmcnt(0) drain).
// EPI: 0 = bf16 store, 1 = f32 store, 2 = f32 store of acc+addF, 3 = gelu->bf16
template <int EPI>
__global__ __launch_bounds__(256, 2)
void gemm_bt(const u16* __restrict__ A, const u16* __restrict__ Bw,
             u16* __restrict__ outB, float* __restrict__ outF,
             const float* __restrict__ addF, int M, int N, int K) {
  __shared__ __align__(16) u16 As[2][128 * 64];
  __shared__ __align__(16) u16 Bs[2][128 * 64];
  const int tid = threadIdx.x;
  const int wave = tid >> 6, lane = tid & 63;
  const int brow = blockIdx.x * 128, bcol = blockIdx.y * 128;
  const int wr = (wave >> 1) * 64, wc = (wave & 1) * 64;
  const int fr = lane & 15, fq = lane >> 4;
  const int srow = lane >> 3;        // 0..7 within an 8-row group
  const int scol = (lane & 7) * 8;   // k element offset (16B chunks)
  f32x4 acc[4][4];
#pragma unroll
  for (int m = 0; m < 4; ++m)
#pragma unroll
    for (int n = 0; n < 4; ++n) acc[m][n] = (f32x4){0.f, 0.f, 0.f, 0.f};

  auto STAGE = [&](int buf, int k0) {
#pragma unroll
    for (int t = 0; t < 4; ++t) {
      const int j = wave * 4 + t;                  // 16 chunks of 8 rows
      const u16* ga = A + (size_t)(brow + j * 8 + srow) * K + (k0 + scol);
      const u16* gb = Bw + (size_t)(bcol + j * 8 + srow) * K + (k0 + scol);
      __builtin_amdgcn_global_load_lds(
          (const __attribute__((address_space(1))) void*)ga,
          (__attribute__((address_space(3))) void*)&As[buf][j * 512], 16, 0, 0);
      __builtin_amdgcn_global_load_lds(
          (const __attribute__((address_space(1))) void*)gb,
          (__attribute__((address_space(3))) void*)&Bs[buf][j * 512], 16, 0, 0);
    }
  };

  STAGE(0, 0);
  __syncthreads();          // drain vmcnt(0): buf0 published
  const int nt = K >> 6;
  int cur = 0;
  for (int t = 0; t < nt; ++t) {
    if (t + 1 < nt) STAGE(cur ^ 1, (t + 1) << 6);  // prefetch next tile FIRST
#pragma unroll
    for (int kk = 0; kk < 2; ++kk) {
      bf16x8 af[4], bfv[4];
#pragma unroll
      for (int m = 0; m < 4; ++m)
        af[m] = *(const bf16x8*)&As[cur][(wr + m * 16 + fr) * 64 + kk * 32 + fq * 8];
#pragma unroll
      for (int n = 0; n < 4; ++n)
        bfv[n] = *(const bf16x8*)&Bs[cur][(wc + n * 16 + fr) * 64 + kk * 32 + fq * 8];
      __builtin_amdgcn_s_setprio(1);
#pragma unroll
      for (int m = 0; m < 4; ++m)
#pragma unroll
        for (int n = 0; n < 4; ++n)
          acc[m][n] = __builtin_amdgcn_mfma_f32_16x16x32_bf16(af[m], bfv[n],
                                                              acc[m][n], 0, 0, 0);
      __builtin_amdgcn_s_setprio(0);
    }
    __syncthreads();       // one barrier per K-step: publishes prefetched tile
    cur ^= 1;
  }

#pragma unroll
  for (int m = 0; m < 4; ++m) {
    const int row0 = brow + wr + m * 16 + fq * 4;
#pragma unroll
    for (int n = 0; n < 4; ++n) {
      const int col = bcol + wc + n * 16 + fr;
#pragma unroll
      for (int j = 0; j < 4; ++j) {
        const size_t o = (size_t)(row0 + j) * N + col;
        const float vv = acc[m][n][j];
        if constexpr (EPI == 0) {
          outB[o] = f2bf(vv);
        } else if constexpr (EPI == 1) {
          outF[o] = vv;
        } else if constexpr (EPI == 2) {
          outF[o] = vv + addF[o];
        } else {
          outB[o] = f2bf(0.5f * vv * (1.0f + erff(vv * 0.70710678118654752f)));
        }
      }
    }
  }
}

// ---------------------------------------------------------------- attention
// One block per (b, qw, h): Q 64x64, K/V 36x64, softmax over 36.
__global__ __launch_bounds__(256)
void attn_kernel(const u16* __restrict__ q, const u16* __restrict__ k,
                 const u16* __restrict__ v, u16* __restrict__ ao) {
  __shared__ __align__(16) u16 Qs[64 * 64];
  __shared__ __align__(16) u16 Ks[36 * 64];
  __shared__ __align__(16) u16 Vs[36 * 64];
  __shared__ float Ps[64 * 36];
  const int bid = blockIdx.x;
  const int h = bid & 15, qw = (bid >> 4) & 15, b = bid >> 8;
  const int tid = threadIdx.x;
  const size_t qbase = ((size_t)b * 1024) * 1024 + (size_t)h * 64;
  for (int i = tid; i < 64 * 16; i += 256) {
    int l = i >> 4, d4 = (i & 15) * 4;
    *(ushort4*)&Qs[l * 64 + d4] =
        *(const ushort4*)&q[qbase + (size_t)(l * 16 + qw) * 1024 + d4];
  }
  const size_t kvbase = ((size_t)(b * 16 + qw)) * 36 * 1024 + (size_t)h * 64;
  for (int i = tid; i < 36 * 16; i += 256) {
    int w = i >> 4, d4 = (i & 15) * 4;
    *(ushort4*)&Ks[w * 64 + d4] = *(const ushort4*)&k[kvbase + (size_t)w * 1024 + d4];
    *(ushort4*)&Vs[w * 64 + d4] = *(const ushort4*)&v[kvbase + (size_t)w * 1024 + d4];
  }
  __syncthreads();
  const int l = tid >> 2, quad = tid & 3;
  float sc[9];
#pragma unroll
  for (int wi = 0; wi < 9; ++wi) {
    int w = quad * 9 + wi;
    float acc = 0.f;
#pragma unroll
    for (int dd = 0; dd < 64; dd += 4) {
      ushort4 qv = *(const ushort4*)&Qs[l * 64 + dd];
      ushort4 kv = *(const ushort4*)&Ks[w * 64 + dd];
      acc += bf2f(qv.x) * bf2f(kv.x) + bf2f(qv.y) * bf2f(kv.y) +
             bf2f(qv.z) * bf2f(kv.z) + bf2f(qv.w) * bf2f(kv.w);
    }
    sc[wi] = acc * 0.125f;
  }
  float mx = sc[0];
#pragma unroll
  for (int wi = 1; wi < 9; ++wi) mx = fmaxf(mx, sc[wi]);
  mx = fmaxf(mx, __shfl_xor(mx, 1));
  mx = fmaxf(mx, __shfl_xor(mx, 2));
  float sum = 0.f;
#pragma unroll
  for (int wi = 0; wi < 9; ++wi) { sc[wi] = __expf(sc[wi] - mx); sum += sc[wi]; }
  sum += __shfl_xor(sum, 1);
  sum += __shfl_xor(sum, 2);
  const float inv = 1.0f / sum;
#pragma unroll
  for (int wi = 0; wi < 9; ++wi) Ps[l * 36 + quad * 9 + wi] = sc[wi] * inv;
  __syncthreads();
  float o[16];
#pragma unroll
  for (int dd = 0; dd < 16; ++dd) o[dd] = 0.f;
  for (int w = 0; w < 36; ++w) {
    float p = Ps[l * 36 + w];
#pragma unroll
    for (int dd = 0; dd < 16; dd += 4) {
      ushort4 vv = *(const ushort4*)&Vs[w * 64 + quad * 16 + dd];
      o[dd] += p * bf2f(vv.x); o[dd + 1] += p * bf2f(vv.y);
      o[dd + 2] += p * bf2f(vv.z); o[dd + 3] += p * bf2f(vv.w);
    }
  }
  const size_t obase = qbase + (size_t)(l * 16 + qw) * 1024 + quad * 16;
#pragma unroll
  for (int dd = 0; dd < 16; dd += 4) {
    ushort4 ov;
    ov.x = f2bf(o[dd]); ov.y = f2bf(o[dd + 1]);
    ov.z = f2bf(o[dd + 2]); ov.w = f2bf(o[dd + 3]);
    *(ushort4*)&ao[obase + dd] = ov;
  }
}

// ---------------------------------------------------------------- launch
extern "C" void kernel_launch(void* const* d_in, const int* in_sizes, int n_in,
                              void* d_out, int out_size, void* d_ws, size_t ws_size,
                              hipStream_t stream) {
  const float* gctx = (const float*)d_in[1];
  const float* queries = (const float*)d_in[4];
  const float* image_tokens = (const float*)d_in[5];
  const float* W_in = (const float*)d_in[7];
  const float* W_ctx = (const float*)d_in[8];
  const float* ln_q_g = (const float*)d_in[9];
  const float* ln_q_b = (const float*)d_in[10];
  const float* Wq = (const float*)d_in[11];
  const float* ln_k_g = (const float*)d_in[12];
  const float* ln_k_b = (const float*)d_in[13];
  const float* Wk = (const float*)d_in[14];
  const float* ln_v_g = (const float*)d_in[15];
  const float* ln_v_b = (const float*)d_in[16];
  const float* Wv = (const float*)d_in[17];
  const float* Wo = (const float*)d_in[18];
  const float* norm_g = (const float*)d_in[19];
  const float* norm_b = (const float*)d_in[20];
  const float* W1 = (const float*)d_in[21];
  const float* W2 = (const float*)d_in[22];
  float* out = (float*)d_out;

  // ---- workspace arena (136 MiB, same layout as round 2) ----
  char* ws = (char*)d_ws;
  const size_t MB = 1024 * 1024;
  u16* w_in_b  = (u16*)(ws + 0 * MB);    // 4 MiB
  u16* w_ctx_b = (u16*)(ws + 4 * MB);
  u16* wq_b    = (u16*)(ws + 6 * MB);
  u16* wk_b    = (u16*)(ws + 8 * MB);
  u16* wv_b    = (u16*)(ws + 10 * MB);
  u16* wo_b    = (u16*)(ws + 12 * MB);
  u16* w1_b    = (u16*)(ws + 14 * MB);
  u16* w2_b    = (u16*)(ws + 16 * MB);
  char* regA = ws + 18 * MB;   // 64 MiB
  char* regB = regA + 64 * MB; // 36 MiB
  char* regC = regB + 36 * MB; // 18 MiB

  u16* acat = (u16*)regA;               // 16384 x 2048 bf16
  u16* pqln = (u16*)regA;               // 16384 x 1024 bf16 (acat dead)
  u16* qmat = (u16*)(regA + 32 * MB);   // 16384 x 1024 bf16
  u16* vln  = (u16*)regA;               // 9216 x 1024 bf16 (pqln dead)
  u16* aoh  = (u16*)regA;               // 16384 x 1024 bf16 (vln dead)
  u16* xmat = (u16*)(regA + 32 * MB);   // 16384 x 1024 bf16 (qmat dead)

  float* winp = (float*)regB;           // 9216 x 1024 f32
  u16* kmat = (u16*)regB;               // 9216 x 1024 bf16 (winp dead)
  u16* vmat = (u16*)(regB + 18 * MB);   // 9216 x 1024 bf16
  u16* gout = (u16*)regB;               // 16384 x 1024 bf16 (kmat/vmat dead)

  u16* gcb = (u16*)regC;                // 9216 x 1024 bf16
  u16* kln = (u16*)regC;                // 9216 x 1024 bf16 (gcb dead)

  float* pq = out;                      // f32 16384 x 1024, lives in d_out

  // ---- single batched convert for all weights + gctx ----
  Cvt9 jobs;
  const float* srcs[9] = {W_in, W_ctx, Wq, Wk, Wv, Wo, W1, W2, gctx};
  u16* dsts[9] = {w_in_b, w_ctx_b, wq_b, wk_b, wv_b, wo_b, w1_b, w2_b, gcb};
  long sizes[9] = {2048l * 1024, 1048576, 1048576, 1048576, 1048576,
                   1048576, 1048576, 1048576, 9216l * 1024};
  long cum = 0;
  for (int j = 0; j < 9; ++j) {
    jobs.s[j] = srcs[j];
    jobs.d[j] = dsts[j];
    jobs.cumv[j] = cum;
    cum += sizes[j] / 4;
  }
  jobs.cumv[9] = cum;
  convert_batch<<<dim3(2048), dim3(256), 0, stream>>>(jobs);
  build_acat<<<dim3(8192), dim3(256), 0, stream>>>(queries, image_tokens, acat);

  // pq = Acat @ W_in^T  (fp32 -> d_out)
  gemm_bt<1><<<dim3(128, 8), dim3(256), 0, stream>>>(acat, w_in_b, nullptr, pq,
                                                     nullptr, 16384, 1024, 2048);
  // ln_q(pq) -> bf16
  ln_rows<<<dim3(16384), dim3(256), 0, stream>>>(pq, ln_q_g, ln_q_b, pqln);
  // q = ln(pq) @ Wq^T  (bf16)
  gemm_bt<0><<<dim3(128, 8), dim3(256), 0, stream>>>(pqln, wq_b, qmat, nullptr,
                                                     nullptr, 16384, 1024, 1024);
  // winp = gctx_bf @ W_ctx^T  (fp32)
  gemm_bt<1><<<dim3(72, 8), dim3(256), 0, stream>>>(gcb, w_ctx_b, nullptr, winp,
                                                    nullptr, 9216, 1024, 1024);
  // gather + ln_k / ln_v -> bf16
  ln_kv<<<dim3(9216), dim3(256), 0, stream>>>(winp, ln_k_g, ln_k_b, ln_v_g,
                                              ln_v_b, kln, vln);
  // k/v projections
  gemm_bt<0><<<dim3(72, 8), dim3(256), 0, stream>>>(kln, wk_b, kmat, nullptr,
                                                    nullptr, 9216, 1024, 1024);
  gemm_bt<0><<<dim3(72, 8), dim3(256), 0, stream>>>(vln, wv_b, vmat, nullptr,
                                                    nullptr, 9216, 1024, 1024);
  // attention
  attn_kernel<<<dim3(4096), dim3(256), 0, stream>>>(qmat, kmat, vmat, aoh);
  // y = ao @ Wo^T + pq  (fp32, in-place in d_out)
  gemm_bt<2><<<dim3(128, 8), dim3(256), 0, stream>>>(aoh, wo_b, nullptr, pq, pq,
                                                     16384, 1024, 1024);
  // x = ln(y) -> bf16
  ln_rows<<<dim3(16384), dim3(256), 0, stream>>>(pq, norm_g, norm_b, xmat);
  // h = gelu(x @ W1^T) -> bf16
  gemm_bt<3><<<dim3(128, 8), dim3(256), 0, stream>>>(xmat, w1_b, gout, nullptr,
                                                     nullptr, 16384, 1024, 1024);
  // out = h @ W2^T + image_tokens  (fp32 -> d_out)
  gemm_bt<2><<<dim3(128, 8), dim3(256), 0, stream>>>(gout, w2_b, nullptr, out,
                                                     image_tokens, 16384, 1024, 1024);
}

// Round 4
// 632.671 us; speedup vs baseline: 1.1333x; 1.0653x over previous
//
#include <hip/hip_runtime.h>
#include <cstdint>
#include <cstddef>

typedef unsigned short u16;
typedef __bf16 bf16_t;
typedef bf16_t bf16x8 __attribute__((ext_vector_type(8)));
typedef float f32x4 __attribute__((ext_vector_type(4)));

#define DEV __device__ __forceinline__

DEV u16 f2bf(float f) {
  unsigned u = __float_as_uint(f);
  u += 0x7fffu + ((u >> 16) & 1u);
  return (u16)(u >> 16);
}
DEV float bf2f(u16 h) {
  return __uint_as_float(((unsigned)h) << 16);
}

// ---------------------------------------------------------------- converts
// One batched kernel for all plain f32->bf16 conversions (8 weights + gctx).
struct Cvt9 {
  const float* s[9];
  u16* d[9];
  long cumv[10];  // cumulative vec4 counts
};

__global__ __launch_bounds__(256)
void convert_batch(Cvt9 jobs) {
  const long total = jobs.cumv[9];
  for (long i = (long)blockIdx.x * 256 + threadIdx.x; i < total;
       i += (long)gridDim.x * 256) {
    int j = 0;
#pragma unroll
    for (int t = 0; t < 8; ++t)
      if (i >= jobs.cumv[t + 1]) j = t + 1;
    const long e = (i - jobs.cumv[j]) * 4;
    float4 v = *(const float4*)(jobs.s[j] + e);
    ushort4 o;
    o.x = f2bf(v.x); o.y = f2bf(v.y); o.z = f2bf(v.z); o.w = f2bf(v.w);
    *(ushort4*)(jobs.d[j] + e) = o;
  }
}

// Acat = [queries | image_tokens] as bf16, 16384 x 2048
__global__ __launch_bounds__(256)
void build_acat(const float* __restrict__ q, const float* __restrict__ it,
                u16* __restrict__ dst) {
  const long total = 16384l * 2048 / 4;
  for (long i = (long)blockIdx.x * 256 + threadIdx.x; i < total;
       i += (long)gridDim.x * 256) {
    long e = i * 4;
    int m = (int)(e >> 11);
    int k = (int)(e & 2047);
    const float* s = (k < 1024) ? (q + (long)m * 1024 + k)
                                : (it + (long)m * 1024 + (k - 1024));
    float4 v = *(const float4*)s;
    ushort4 o;
    o.x = f2bf(v.x); o.y = f2bf(v.y); o.z = f2bf(v.z); o.w = f2bf(v.w);
    *(ushort4*)(dst + e) = o;
  }
}

// ---------------------------------------------------------------- layernorm
__global__ __launch_bounds__(256)
void ln_rows(const float* __restrict__ x, const float* __restrict__ g,
             const float* __restrict__ b, u16* __restrict__ out) {
  __shared__ float red[8];
  const int row = blockIdx.x, tid = threadIdx.x;
  const float* xr = x + (size_t)row * 1024;
  float4 v = *(const float4*)(xr + tid * 4);
  float s = v.x + v.y + v.z + v.w;
  float ss = v.x * v.x + v.y * v.y + v.z * v.z + v.w * v.w;
#pragma unroll
  for (int o = 32; o > 0; o >>= 1) { s += __shfl_xor(s, o); ss += __shfl_xor(ss, o); }
  if ((tid & 63) == 0) { red[tid >> 6] = s; red[4 + (tid >> 6)] = ss; }
  __syncthreads();
  s = red[0] + red[1] + red[2] + red[3];
  ss = red[4] + red[5] + red[6] + red[7];
  const float mean = s * 0.0009765625f;
  const float var = ss * 0.0009765625f - mean * mean;
  const float rinv = rsqrtf(var + 1e-5f);
  const int c = tid * 4;
  float4 gg = *(const float4*)(g + c);
  float4 bb = *(const float4*)(b + c);
  ushort4 o4;
  o4.x = f2bf((v.x - mean) * rinv * gg.x + bb.x);
  o4.y = f2bf((v.y - mean) * rinv * gg.y + bb.y);
  o4.z = f2bf((v.z - mean) * rinv * gg.z + bb.z);
  o4.w = f2bf((v.w - mean) * rinv * gg.w + bb.w);
  *(ushort4*)(out + (size_t)row * 1024 + c) = o4;
}

// K/V layernorm with the window gather folded in.
__global__ __launch_bounds__(256)
void ln_kv(const float* __restrict__ winp,
           const float* __restrict__ gk, const float* __restrict__ bk,
           const float* __restrict__ gv, const float* __restrict__ bv,
           u16* __restrict__ kout, u16* __restrict__ vout) {
  __shared__ float red[8];
  const int m = blockIdx.x, tid = threadIdx.x;
  const int b = m / 576, rem = m % 576;
  const int qw = rem / 36, w = rem % 36;
  const int gidx = (qw >> 2) * 144 + (w / 6) * 24 + (qw & 3) * 6 + (w % 6);
  const float* xr = winp + ((size_t)b * 576 + gidx) * 1024;
  float4 v = *(const float4*)(xr + tid * 4);
  float s = v.x + v.y + v.z + v.w;
  float ss = v.x * v.x + v.y * v.y + v.z * v.z + v.w * v.w;
#pragma unroll
  for (int o = 32; o > 0; o >>= 1) { s += __shfl_xor(s, o); ss += __shfl_xor(ss, o); }
  if ((tid & 63) == 0) { red[tid >> 6] = s; red[4 + (tid >> 6)] = ss; }
  __syncthreads();
  s = red[0] + red[1] + red[2] + red[3];
  ss = red[4] + red[5] + red[6] + red[7];
  const float mean = s * 0.0009765625f;
  const float var = ss * 0.0009765625f - mean * mean;
  const float rinv = rsqrtf(var + 1e-5f);
  const int c = tid * 4;
  float4 gg = *(const float4*)(gk + c);
  float4 bb = *(const float4*)(bk + c);
  float4 g2 = *(const float4*)(gv + c);
  float4 b2 = *(const float4*)(bv + c);
  float nx = (v.x - mean) * rinv, ny = (v.y - mean) * rinv;
  float nz = (v.z - mean) * rinv, nw = (v.w - mean) * rinv;
  ushort4 ok, ov;
  ok.x = f2bf(nx * gg.x + bb.x); ok.y = f2bf(ny * gg.y + bb.y);
  ok.z = f2bf(nz * gg.z + bb.z); ok.w = f2bf(nw * gg.w + bb.w);
  ov.x = f2bf(nx * g2.x + b2.x); ov.y = f2bf(ny * g2.y + b2.y);
  ov.z = f2bf(nz * g2.z + b2.z); ov.w = f2bf(nw * g2.w + b2.w);
  *(ushort4*)(kout + (size_t)m * 1024 + c) = ok;
  *(ushort4*)(vout + (size_t)m * 1024 + c) = ov;
}

// ---------------------------------------------------------------- GEMM
// C[M,N] = A[M,K] * B[N,K]^T  (bf16 in, fp32 acc), 128x128 tile, BK=64,
// double-buffered LDS, 2-phase pipeline, ONE barrier per K-step.
//
// Bank-conflict fix (rule #21, both-sides-or-neither with global_load_lds):
//   LDS tile is [128 rows][8 chunks of 16B]. Linear layout would put every
//   row's chunk c in the same bank (row stride 128B -> 16-way conflict,
//   measured 2.5e7 conflicts = ~24 cyc/read). Instead LDS slot (row, s)
//   holds global chunk (s ^ (row&7)):
//     - write side: LDS dest stays linear (gload_lds requires it); the
//       per-lane GLOBAL column is inverse-swizzled: chunk_g = (lane&7)^srow.
//     - read side: chunk slot = (kk*4+fq) ^ (fr&7).
//   XOR is an involution -> same permutation both sides, data identical.
// EPI: 0 = bf16 store, 1 = f32 store, 2 = f32 store of acc+addF, 3 = gelu->bf16
template <int EPI>
__global__ __launch_bounds__(256, 2)
void gemm_bt(const u16* __restrict__ A, const u16* __restrict__ Bw,
             u16* __restrict__ outB, float* __restrict__ outF,
             const float* __restrict__ addF, int M, int N, int K) {
  __shared__ __align__(16) u16 As[2][128 * 64];
  __shared__ __align__(16) u16 Bs[2][128 * 64];
  const int tid = threadIdx.x;
  const int wave = tid >> 6, lane = tid & 63;
  const int brow = blockIdx.x * 128, bcol = blockIdx.y * 128;
  const int wr = (wave >> 1) * 64, wc = (wave & 1) * 64;
  const int fr = lane & 15, fq = lane >> 4;
  const int srow = lane >> 3;                    // 0..7 row within 8-row group
  const int scol = ((lane & 7) ^ srow) * 8;      // inverse-swizzled global chunk
  f32x4 acc[4][4];
#pragma unroll
  for (int m = 0; m < 4; ++m)
#pragma unroll
    for (int n = 0; n < 4; ++n) acc[m][n] = (f32x4){0.f, 0.f, 0.f, 0.f};

  auto STAGE = [&](int buf, int k0) {
#pragma unroll
    for (int t = 0; t < 4; ++t) {
      const int j = wave * 4 + t;                  // 16 chunks of 8 rows
      const u16* ga = A + (size_t)(brow + j * 8 + srow) * K + (k0 + scol);
      const u16* gb = Bw + (size_t)(bcol + j * 8 + srow) * K + (k0 + scol);
      __builtin_amdgcn_global_load_lds(
          (const __attribute__((address_space(1))) void*)ga,
          (__attribute__((address_space(3))) void*)&As[buf][j * 512], 16, 0, 0);
      __builtin_amdgcn_global_load_lds(
          (const __attribute__((address_space(1))) void*)gb,
          (__attribute__((address_space(3))) void*)&Bs[buf][j * 512], 16, 0, 0);
    }
  };

  STAGE(0, 0);
  __syncthreads();          // drain vmcnt(0): buf0 published
  const int nt = K >> 6;
  int cur = 0;
  const int fx = fr & 7;    // read-side swizzle key
  for (int t = 0; t < nt; ++t) {
    if (t + 1 < nt) STAGE(cur ^ 1, (t + 1) << 6);  // prefetch next tile FIRST
#pragma unroll
    for (int kk = 0; kk < 2; ++kk) {
      bf16x8 af[4], bfv[4];
      const int cs = ((kk * 4 + fq) ^ fx) * 8;     // swizzled chunk offset
#pragma unroll
      for (int m = 0; m < 4; ++m)
        af[m] = *(const bf16x8*)&As[cur][(wr + m * 16 + fr) * 64 + cs];
#pragma unroll
      for (int n = 0; n < 4; ++n)
        bfv[n] = *(const bf16x8*)&Bs[cur][(wc + n * 16 + fr) * 64 + cs];
      __builtin_amdgcn_s_setprio(1);
#pragma unroll
      for (int m = 0; m < 4; ++m)
#pragma unroll
        for (int n = 0; n < 4; ++n)
          acc[m][n] = __builtin_amdgcn_mfma_f32_16x16x32_bf16(af[m], bfv[n],
                                                              acc[m][n], 0, 0, 0);
      __builtin_amdgcn_s_setprio(0);
    }
    __syncthreads();       // one barrier per K-step: publishes prefetched tile
    cur ^= 1;
  }

#pragma unroll
  for (int m = 0; m < 4; ++m) {
    const int row0 = brow + wr + m * 16 + fq * 4;
#pragma unroll
    for (int n = 0; n < 4; ++n) {
      const int col = bcol + wc + n * 16 + fr;
#pragma unroll
      for (int j = 0; j < 4; ++j) {
        const size_t o = (size_t)(row0 + j) * N + col;
        const float vv = acc[m][n][j];
        if constexpr (EPI == 0) {
          outB[o] = f2bf(vv);
        } else if constexpr (EPI == 1) {
          outF[o] = vv;
        } else if constexpr (EPI == 2) {
          outF[o] = vv + addF[o];
        } else {
          outB[o] = f2bf(0.5f * vv * (1.0f + erff(vv * 0.70710678118654752f)));
        }
      }
    }
  }
}

// ---------------------------------------------------------------- attention
// One block per (b, qw, h): Q 64x64, K/V 36x64, softmax over 36.
__global__ __launch_bounds__(256)
void attn_kernel(const u16* __restrict__ q, const u16* __restrict__ k,
                 const u16* __restrict__ v, u16* __restrict__ ao) {
  __shared__ __align__(16) u16 Qs[64 * 64];
  __shared__ __align__(16) u16 Ks[36 * 64];
  __shared__ __align__(16) u16 Vs[36 * 64];
  __shared__ float Ps[64 * 36];
  const int bid = blockIdx.x;
  const int h = bid & 15, qw = (bid >> 4) & 15, b = bid >> 8;
  const int tid = threadIdx.x;
  const size_t qbase = ((size_t)b * 1024) * 1024 + (size_t)h * 64;
  for (int i = tid; i < 64 * 16; i += 256) {
    int l = i >> 4, d4 = (i & 15) * 4;
    *(ushort4*)&Qs[l * 64 + d4] =
        *(const ushort4*)&q[qbase + (size_t)(l * 16 + qw) * 1024 + d4];
  }
  const size_t kvbase = ((size_t)(b * 16 + qw)) * 36 * 1024 + (size_t)h * 64;
  for (int i = tid; i < 36 * 16; i += 256) {
    int w = i >> 4, d4 = (i & 15) * 4;
    *(ushort4*)&Ks[w * 64 + d4] = *(const ushort4*)&k[kvbase + (size_t)w * 1024 + d4];
    *(ushort4*)&Vs[w * 64 + d4] = *(const ushort4*)&v[kvbase + (size_t)w * 1024 + d4];
  }
  __syncthreads();
  const int l = tid >> 2, quad = tid & 3;
  float sc[9];
#pragma unroll
  for (int wi = 0; wi < 9; ++wi) {
    int w = quad * 9 + wi;
    float acc = 0.f;
#pragma unroll
    for (int dd = 0; dd < 64; dd += 4) {
      ushort4 qv = *(const ushort4*)&Qs[l * 64 + dd];
      ushort4 kv = *(const ushort4*)&Ks[w * 64 + dd];
      acc += bf2f(qv.x) * bf2f(kv.x) + bf2f(qv.y) * bf2f(kv.y) +
             bf2f(qv.z) * bf2f(kv.z) + bf2f(qv.w) * bf2f(kv.w);
    }
    sc[wi] = acc * 0.125f;
  }
  float mx = sc[0];
#pragma unroll
  for (int wi = 1; wi < 9; ++wi) mx = fmaxf(mx, sc[wi]);
  mx = fmaxf(mx, __shfl_xor(mx, 1));
  mx = fmaxf(mx, __shfl_xor(mx, 2));
  float sum = 0.f;
#pragma unroll
  for (int wi = 0; wi < 9; ++wi) { sc[wi] = __expf(sc[wi] - mx); sum += sc[wi]; }
  sum += __shfl_xor(sum, 1);
  sum += __shfl_xor(sum, 2);
  const float inv = 1.0f / sum;
#pragma unroll
  for (int wi = 0; wi < 9; ++wi) Ps[l * 36 + quad * 9 + wi] = sc[wi] * inv;
  __syncthreads();
  float o[16];
#pragma unroll
  for (int dd = 0; dd < 16; ++dd) o[dd] = 0.f;
  for (int w = 0; w < 36; ++w) {
    float p = Ps[l * 36 + w];
#pragma unroll
    for (int dd = 0; dd < 16; dd += 4) {
      ushort4 vv = *(const ushort4*)&Vs[w * 64 + quad * 16 + dd];
      o[dd] += p * bf2f(vv.x); o[dd + 1] += p * bf2f(vv.y);
      o[dd + 2] += p * bf2f(vv.z); o[dd + 3] += p * bf2f(vv.w);
    }
  }
  const size_t obase = qbase + (size_t)(l * 16 + qw) * 1024 + quad * 16;
#pragma unroll
  for (int dd = 0; dd < 16; dd += 4) {
    ushort4 ov;
    ov.x = f2bf(o[dd]); ov.y = f2bf(o[dd + 1]);
    ov.z = f2bf(o[dd + 2]); ov.w = f2bf(o[dd + 3]);
    *(ushort4*)&ao[obase + dd] = ov;
  }
}

// ---------------------------------------------------------------- launch
extern "C" void kernel_launch(void* const* d_in, const int* in_sizes, int n_in,
                              void* d_out, int out_size, void* d_ws, size_t ws_size,
                              hipStream_t stream) {
  const float* gctx = (const float*)d_in[1];
  const float* queries = (const float*)d_in[4];
  const float* image_tokens = (const float*)d_in[5];
  const float* W_in = (const float*)d_in[7];
  const float* W_ctx = (const float*)d_in[8];
  const float* ln_q_g = (const float*)d_in[9];
  const float* ln_q_b = (const float*)d_in[10];
  const float* Wq = (const float*)d_in[11];
  const float* ln_k_g = (const float*)d_in[12];
  const float* ln_k_b = (const float*)d_in[13];
  const float* Wk = (const float*)d_in[14];
  const float* ln_v_g = (const float*)d_in[15];
  const float* ln_v_b = (const float*)d_in[16];
  const float* Wv = (const float*)d_in[17];
  const float* Wo = (const float*)d_in[18];
  const float* norm_g = (const float*)d_in[19];
  const float* norm_b = (const float*)d_in[20];
  const float* W1 = (const float*)d_in[21];
  const float* W2 = (const float*)d_in[22];
  float* out = (float*)d_out;

  // ---- workspace arena (136 MiB, same layout as round 2) ----
  char* ws = (char*)d_ws;
  const size_t MB = 1024 * 1024;
  u16* w_in_b  = (u16*)(ws + 0 * MB);    // 4 MiB
  u16* w_ctx_b = (u16*)(ws + 4 * MB);
  u16* wq_b    = (u16*)(ws + 6 * MB);
  u16* wk_b    = (u16*)(ws + 8 * MB);
  u16* wv_b    = (u16*)(ws + 10 * MB);
  u16* wo_b    = (u16*)(ws + 12 * MB);
  u16* w1_b    = (u16*)(ws + 14 * MB);
  u16* w2_b    = (u16*)(ws + 16 * MB);
  char* regA = ws + 18 * MB;   // 64 MiB
  char* regB = regA + 64 * MB; // 36 MiB
  char* regC = regB + 36 * MB; // 18 MiB

  u16* acat = (u16*)regA;               // 16384 x 2048 bf16
  u16* pqln = (u16*)regA;               // 16384 x 1024 bf16 (acat dead)
  u16* qmat = (u16*)(regA + 32 * MB);   // 16384 x 1024 bf16
  u16* vln  = (u16*)regA;               // 9216 x 1024 bf16 (pqln dead)
  u16* aoh  = (u16*)regA;               // 16384 x 1024 bf16 (vln dead)
  u16* xmat = (u16*)(regA + 32 * MB);   // 16384 x 1024 bf16 (qmat dead)

  float* winp = (float*)regB;           // 9216 x 1024 f32
  u16* kmat = (u16*)regB;               // 9216 x 1024 bf16 (winp dead)
  u16* vmat = (u16*)(regB + 18 * MB);   // 9216 x 1024 bf16
  u16* gout = (u16*)regB;               // 16384 x 1024 bf16 (kmat/vmat dead)

  u16* gcb = (u16*)regC;                // 9216 x 1024 bf16
  u16* kln = (u16*)regC;                // 9216 x 1024 bf16 (gcb dead)

  float* pq = out;                      // f32 16384 x 1024, lives in d_out

  // ---- single batched convert for all weights + gctx ----
  Cvt9 jobs;
  const float* srcs[9] = {W_in, W_ctx, Wq, Wk, Wv, Wo, W1, W2, gctx};
  u16* dsts[9] = {w_in_b, w_ctx_b, wq_b, wk_b, wv_b, wo_b, w1_b, w2_b, gcb};
  long sizes[9] = {2048l * 1024, 1048576, 1048576, 1048576, 1048576,
                   1048576, 1048576, 1048576, 9216l * 1024};
  long cum = 0;
  for (int j = 0; j < 9; ++j) {
    jobs.s[j] = srcs[j];
    jobs.d[j] = dsts[j];
    jobs.cumv[j] = cum;
    cum += sizes[j] / 4;
  }
  jobs.cumv[9] = cum;
  convert_batch<<<dim3(2048), dim3(256), 0, stream>>>(jobs);
  build_acat<<<dim3(8192), dim3(256), 0, stream>>>(queries, image_tokens, acat);

  // pq = Acat @ W_in^T  (fp32 -> d_out)
  gemm_bt<1><<<dim3(128, 8), dim3(256), 0, stream>>>(acat, w_in_b, nullptr, pq,
                                                     nullptr, 16384, 1024, 2048);
  // ln_q(pq) -> bf16
  ln_rows<<<dim3(16384), dim3(256), 0, stream>>>(pq, ln_q_g, ln_q_b, pqln);
  // q = ln(pq) @ Wq^T  (bf16)
  gemm_bt<0><<<dim3(128, 8), dim3(256), 0, stream>>>(pqln, wq_b, qmat, nullptr,
                                                     nullptr, 16384, 1024, 1024);
  // winp = gctx_bf @ W_ctx^T  (fp32)
  gemm_bt<1><<<dim3(72, 8), dim3(256), 0, stream>>>(gcb, w_ctx_b, nullptr, winp,
                                                    nullptr, 9216, 1024, 1024);
  // gather + ln_k / ln_v -> bf16
  ln_kv<<<dim3(9216), dim3(256), 0, stream>>>(winp, ln_k_g, ln_k_b, ln_v_g,
                                              ln_v_b, kln, vln);
  // k/v projections
  gemm_bt<0><<<dim3(72, 8), dim3(256), 0, stream>>>(kln, wk_b, kmat, nullptr,
                                                    nullptr, 9216, 1024, 1024);
  gemm_bt<0><<<dim3(72, 8), dim3(256), 0, stream>>>(vln, wv_b, vmat, nullptr,
                                                    nullptr, 9216, 1024, 1024);
  // attention
  attn_kernel<<<dim3(4096), dim3(256), 0, stream>>>(qmat, kmat, vmat, aoh);
  // y = ao @ Wo^T + pq  (fp32, in-place in d_out)
  gemm_bt<2><<<dim3(128, 8), dim3(256), 0, stream>>>(aoh, wo_b, nullptr, pq, pq,
                                                     16384, 1024, 1024);
  // x = ln(y) -> bf16
  ln_rows<<<dim3(16384), dim3(256), 0, stream>>>(pq, norm_g, norm_b, xmat);
  // h = gelu(x @ W1^T) -> bf16
  gemm_bt<3><<<dim3(128, 8), dim3(256), 0, stream>>>(xmat, w1_b, gout, nullptr,
                                                     nullptr, 16384, 1024, 1024);
  // out = h @ W2^T + image_tokens  (fp32 -> d_out)
  gemm_bt<2><<<dim3(128, 8), dim3(256), 0, stream>>>(gout, w2_b, nullptr, out,
                                                     image_tokens, 16384, 1024, 1024);
}

// Round 5
// 603.072 us; speedup vs baseline: 1.1889x; 1.0491x over previous
//
#include <hip/hip_runtime.h>
#include <cstdint>
#include <cstddef>

typedef unsigned short u16;
typedef __bf16 bf16_t;
typedef bf16_t bf16x8 __attribute__((ext_vector_type(8)));
typedef float f32x4 __attribute__((ext_vector_type(4)));

#define DEV __device__ __forceinline__

DEV u16 f2bf(float f) {
  unsigned u = __float_as_uint(f);
  u += 0x7fffu + ((u >> 16) & 1u);
  return (u16)(u >> 16);
}
DEV float bf2f(u16 h) {
  return __uint_as_float(((unsigned)h) << 16);
}

// ---------------------------------------------------------------- converts
// One batched kernel for all plain f32->bf16 conversions (8 weights + gctx).
struct Cvt9 {
  const float* s[9];
  u16* d[9];
  long cumv[10];  // cumulative vec4 counts
};

__global__ __launch_bounds__(256)
void convert_batch(Cvt9 jobs) {
  const long total = jobs.cumv[9];
  for (long i = (long)blockIdx.x * 256 + threadIdx.x; i < total;
       i += (long)gridDim.x * 256) {
    int j = 0;
#pragma unroll
    for (int t = 0; t < 8; ++t)
      if (i >= jobs.cumv[t + 1]) j = t + 1;
    const long e = (i - jobs.cumv[j]) * 4;
    float4 v = *(const float4*)(jobs.s[j] + e);
    ushort4 o;
    o.x = f2bf(v.x); o.y = f2bf(v.y); o.z = f2bf(v.z); o.w = f2bf(v.w);
    *(ushort4*)(jobs.d[j] + e) = o;
  }
}

// Acat = [queries | image_tokens] as bf16, 16384 x 2048
__global__ __launch_bounds__(256)
void build_acat(const float* __restrict__ q, const float* __restrict__ it,
                u16* __restrict__ dst) {
  const long total = 16384l * 2048 / 4;
  for (long i = (long)blockIdx.x * 256 + threadIdx.x; i < total;
       i += (long)gridDim.x * 256) {
    long e = i * 4;
    int m = (int)(e >> 11);
    int k = (int)(e & 2047);
    const float* s = (k < 1024) ? (q + (long)m * 1024 + k)
                                : (it + (long)m * 1024 + (k - 1024));
    float4 v = *(const float4*)s;
    ushort4 o;
    o.x = f2bf(v.x); o.y = f2bf(v.y); o.z = f2bf(v.z); o.w = f2bf(v.w);
    *(ushort4*)(dst + e) = o;
  }
}

// ---------------------------------------------------------------- layernorm
__global__ __launch_bounds__(256)
void ln_rows(const float* __restrict__ x, const float* __restrict__ g,
             const float* __restrict__ b, u16* __restrict__ out) {
  __shared__ float red[8];
  const int row = blockIdx.x, tid = threadIdx.x;
  const float* xr = x + (size_t)row * 1024;
  float4 v = *(const float4*)(xr + tid * 4);
  float s = v.x + v.y + v.z + v.w;
  float ss = v.x * v.x + v.y * v.y + v.z * v.z + v.w * v.w;
#pragma unroll
  for (int o = 32; o > 0; o >>= 1) { s += __shfl_xor(s, o); ss += __shfl_xor(ss, o); }
  if ((tid & 63) == 0) { red[tid >> 6] = s; red[4 + (tid >> 6)] = ss; }
  __syncthreads();
  s = red[0] + red[1] + red[2] + red[3];
  ss = red[4] + red[5] + red[6] + red[7];
  const float mean = s * 0.0009765625f;
  const float var = ss * 0.0009765625f - mean * mean;
  const float rinv = rsqrtf(var + 1e-5f);
  const int c = tid * 4;
  float4 gg = *(const float4*)(g + c);
  float4 bb = *(const float4*)(b + c);
  ushort4 o4;
  o4.x = f2bf((v.x - mean) * rinv * gg.x + bb.x);
  o4.y = f2bf((v.y - mean) * rinv * gg.y + bb.y);
  o4.z = f2bf((v.z - mean) * rinv * gg.z + bb.z);
  o4.w = f2bf((v.w - mean) * rinv * gg.w + bb.w);
  *(ushort4*)(out + (size_t)row * 1024 + c) = o4;
}

// K/V layernorm with the window gather folded in.
__global__ __launch_bounds__(256)
void ln_kv(const float* __restrict__ winp,
           const float* __restrict__ gk, const float* __restrict__ bk,
           const float* __restrict__ gv, const float* __restrict__ bv,
           u16* __restrict__ kout, u16* __restrict__ vout) {
  __shared__ float red[8];
  const int m = blockIdx.x, tid = threadIdx.x;
  const int b = m / 576, rem = m % 576;
  const int qw = rem / 36, w = rem % 36;
  const int gidx = (qw >> 2) * 144 + (w / 6) * 24 + (qw & 3) * 6 + (w % 6);
  const float* xr = winp + ((size_t)b * 576 + gidx) * 1024;
  float4 v = *(const float4*)(xr + tid * 4);
  float s = v.x + v.y + v.z + v.w;
  float ss = v.x * v.x + v.y * v.y + v.z * v.z + v.w * v.w;
#pragma unroll
  for (int o = 32; o > 0; o >>= 1) { s += __shfl_xor(s, o); ss += __shfl_xor(ss, o); }
  if ((tid & 63) == 0) { red[tid >> 6] = s; red[4 + (tid >> 6)] = ss; }
  __syncthreads();
  s = red[0] + red[1] + red[2] + red[3];
  ss = red[4] + red[5] + red[6] + red[7];
  const float mean = s * 0.0009765625f;
  const float var = ss * 0.0009765625f - mean * mean;
  const float rinv = rsqrtf(var + 1e-5f);
  const int c = tid * 4;
  float4 gg = *(const float4*)(gk + c);
  float4 bb = *(const float4*)(bk + c);
  float4 g2 = *(const float4*)(gv + c);
  float4 b2 = *(const float4*)(bv + c);
  float nx = (v.x - mean) * rinv, ny = (v.y - mean) * rinv;
  float nz = (v.z - mean) * rinv, nw = (v.w - mean) * rinv;
  ushort4 ok, ov;
  ok.x = f2bf(nx * gg.x + bb.x); ok.y = f2bf(ny * gg.y + bb.y);
  ok.z = f2bf(nz * gg.z + bb.z); ok.w = f2bf(nw * gg.w + bb.w);
  ov.x = f2bf(nx * g2.x + b2.x); ov.y = f2bf(ny * g2.y + b2.y);
  ov.z = f2bf(nz * g2.z + b2.z); ov.w = f2bf(nw * g2.w + b2.w);
  *(ushort4*)(kout + (size_t)m * 1024 + c) = ok;
  *(ushort4*)(vout + (size_t)m * 1024 + c) = ov;
}

// ---------------------------------------------------------------- GEMM
// C[M,N] = A[M,K] * B[N,K]^T  (bf16 in, fp32 acc), 128x128 tile, BK=64,
// single-buffered LDS (32 KB -> 3 blocks/CU, cross-block latency hiding),
// m97 2-barrier K-loop.  N must be 1024 (all GEMMs here are N=1024).
//
// XCD swizzle (T1): 1D grid, nwg % 8 == 0. XCD (bid&7) owns a contiguous
// M-stripe of rows_per_chunk row-tiles x 8 col-tiles, so its A working set
// (<=4 MiB) fits the per-XCD L2 and A re-reads across bcol become L2 hits.
//
// Bank swizzle (verified round 4: conflicts 2.5e7 -> 0): LDS slot (row,s)
// holds global chunk (s ^ (row&7)); write side inverse-swizzles the GLOBAL
// column (LDS dest stays linear for global_load_lds); read side XORs.
// EPI: 0 = bf16 store, 1 = f32 store, 2 = f32 store of acc+addF, 3 = gelu->bf16
template <int EPI>
__global__ __launch_bounds__(256)
void gemm_bt(const u16* __restrict__ A, const u16* __restrict__ Bw,
             u16* __restrict__ outB, float* __restrict__ outF,
             const float* __restrict__ addF, int M, int N, int K) {
  __shared__ __align__(16) u16 As[128 * 64];
  __shared__ __align__(16) u16 Bs[128 * 64];
  const int tid = threadIdx.x;
  const int wave = tid >> 6, lane = tid & 63;
  // ---- XCD-chunked block swizzle (N==1024 -> 8 col-tiles) ----
  const int bid = blockIdx.x;
  const int rpc = gridDim.x >> 6;              // rows_per_chunk = M/1024
  const int xcd = bid & 7, slot = bid >> 3;
  const int brow = (xcd * rpc + (slot >> 3)) << 7;
  const int bcol = (slot & 7) << 7;
  const int wr = (wave >> 1) * 64, wc = (wave & 1) * 64;
  const int fr = lane & 15, fq = lane >> 4;
  const int srow = lane >> 3;                    // 0..7 row within 8-row group
  const int scol = ((lane & 7) ^ srow) * 8;      // inverse-swizzled global chunk
  f32x4 acc[4][4];
#pragma unroll
  for (int m = 0; m < 4; ++m)
#pragma unroll
    for (int n = 0; n < 4; ++n) acc[m][n] = (f32x4){0.f, 0.f, 0.f, 0.f};

  const int fx = fr & 7;    // read-side swizzle key
  for (int k0 = 0; k0 < K; k0 += 64) {
#pragma unroll
    for (int t = 0; t < 4; ++t) {
      const int j = wave * 4 + t;                  // 16 chunks of 8 rows
      const u16* ga = A + (size_t)(brow + j * 8 + srow) * K + (k0 + scol);
      const u16* gb = Bw + (size_t)(bcol + j * 8 + srow) * K + (k0 + scol);
      __builtin_amdgcn_global_load_lds(
          (const __attribute__((address_space(1))) void*)ga,
          (__attribute__((address_space(3))) void*)&As[j * 512], 16, 0, 0);
      __builtin_amdgcn_global_load_lds(
          (const __attribute__((address_space(1))) void*)gb,
          (__attribute__((address_space(3))) void*)&Bs[j * 512], 16, 0, 0);
    }
    __syncthreads();
#pragma unroll
    for (int kk = 0; kk < 2; ++kk) {
      bf16x8 af[4], bfv[4];
      const int cs = ((kk * 4 + fq) ^ fx) * 8;     // swizzled chunk offset
#pragma unroll
      for (int m = 0; m < 4; ++m)
        af[m] = *(const bf16x8*)&As[(wr + m * 16 + fr) * 64 + cs];
#pragma unroll
      for (int n = 0; n < 4; ++n)
        bfv[n] = *(const bf16x8*)&Bs[(wc + n * 16 + fr) * 64 + cs];
#pragma unroll
      for (int m = 0; m < 4; ++m)
#pragma unroll
        for (int n = 0; n < 4; ++n)
          acc[m][n] = __builtin_amdgcn_mfma_f32_16x16x32_bf16(af[m], bfv[n],
                                                              acc[m][n], 0, 0, 0);
    }
    __syncthreads();
  }

#pragma unroll
  for (int m = 0; m < 4; ++m) {
    const int row0 = brow + wr + m * 16 + fq * 4;
#pragma unroll
    for (int n = 0; n < 4; ++n) {
      const int col = bcol + wc + n * 16 + fr;
#pragma unroll
      for (int j = 0; j < 4; ++j) {
        const size_t o = (size_t)(row0 + j) * N + col;
        const float vv = acc[m][n][j];
        if constexpr (EPI == 0) {
          outB[o] = f2bf(vv);
        } else if constexpr (EPI == 1) {
          outF[o] = vv;
        } else if constexpr (EPI == 2) {
          outF[o] = vv + addF[o];
        } else {
          outB[o] = f2bf(0.5f * vv * (1.0f + erff(vv * 0.70710678118654752f)));
        }
      }
    }
  }
}

// ---------------------------------------------------------------- attention
// One block per (b, qw, h): Q 64x64, K/V 36x64, softmax over 36.
__global__ __launch_bounds__(256)
void attn_kernel(const u16* __restrict__ q, const u16* __restrict__ k,
                 const u16* __restrict__ v, u16* __restrict__ ao) {
  __shared__ __align__(16) u16 Qs[64 * 64];
  __shared__ __align__(16) u16 Ks[36 * 64];
  __shared__ __align__(16) u16 Vs[36 * 64];
  __shared__ float Ps[64 * 36];
  const int bid = blockIdx.x;
  const int h = bid & 15, qw = (bid >> 4) & 15, b = bid >> 8;
  const int tid = threadIdx.x;
  const size_t qbase = ((size_t)b * 1024) * 1024 + (size_t)h * 64;
  for (int i = tid; i < 64 * 16; i += 256) {
    int l = i >> 4, d4 = (i & 15) * 4;
    *(ushort4*)&Qs[l * 64 + d4] =
        *(const ushort4*)&q[qbase + (size_t)(l * 16 + qw) * 1024 + d4];
  }
  const size_t kvbase = ((size_t)(b * 16 + qw)) * 36 * 1024 + (size_t)h * 64;
  for (int i = tid; i < 36 * 16; i += 256) {
    int w = i >> 4, d4 = (i & 15) * 4;
    *(ushort4*)&Ks[w * 64 + d4] = *(const ushort4*)&k[kvbase + (size_t)w * 1024 + d4];
    *(ushort4*)&Vs[w * 64 + d4] = *(const ushort4*)&v[kvbase + (size_t)w * 1024 + d4];
  }
  __syncthreads();
  const int l = tid >> 2, quad = tid & 3;
  float sc[9];
#pragma unroll
  for (int wi = 0; wi < 9; ++wi) {
    int w = quad * 9 + wi;
    float acc = 0.f;
#pragma unroll
    for (int dd = 0; dd < 64; dd += 4) {
      ushort4 qv = *(const ushort4*)&Qs[l * 64 + dd];
      ushort4 kv = *(const ushort4*)&Ks[w * 64 + dd];
      acc += bf2f(qv.x) * bf2f(kv.x) + bf2f(qv.y) * bf2f(kv.y) +
             bf2f(qv.z) * bf2f(kv.z) + bf2f(qv.w) * bf2f(kv.w);
    }
    sc[wi] = acc * 0.125f;
  }
  float mx = sc[0];
#pragma unroll
  for (int wi = 1; wi < 9; ++wi) mx = fmaxf(mx, sc[wi]);
  mx = fmaxf(mx, __shfl_xor(mx, 1));
  mx = fmaxf(mx, __shfl_xor(mx, 2));
  float sum = 0.f;
#pragma unroll
  for (int wi = 0; wi < 9; ++wi) { sc[wi] = __expf(sc[wi] - mx); sum += sc[wi]; }
  sum += __shfl_xor(sum, 1);
  sum += __shfl_xor(sum, 2);
  const float inv = 1.0f / sum;
#pragma unroll
  for (int wi = 0; wi < 9; ++wi) Ps[l * 36 + quad * 9 + wi] = sc[wi] * inv;
  __syncthreads();
  float o[16];
#pragma unroll
  for (int dd = 0; dd < 16; ++dd) o[dd] = 0.f;
  for (int w = 0; w < 36; ++w) {
    float p = Ps[l * 36 + w];
#pragma unroll
    for (int dd = 0; dd < 16; dd += 4) {
      ushort4 vv = *(const ushort4*)&Vs[w * 64 + quad * 16 + dd];
      o[dd] += p * bf2f(vv.x); o[dd + 1] += p * bf2f(vv.y);
      o[dd + 2] += p * bf2f(vv.z); o[dd + 3] += p * bf2f(vv.w);
    }
  }
  const size_t obase = qbase + (size_t)(l * 16 + qw) * 1024 + quad * 16;
#pragma unroll
  for (int dd = 0; dd < 16; dd += 4) {
    ushort4 ov;
    ov.x = f2bf(o[dd]); ov.y = f2bf(o[dd + 1]);
    ov.z = f2bf(o[dd + 2]); ov.w = f2bf(o[dd + 3]);
    *(ushort4*)&ao[obase + dd] = ov;
  }
}

// ---------------------------------------------------------------- launch
extern "C" void kernel_launch(void* const* d_in, const int* in_sizes, int n_in,
                              void* d_out, int out_size, void* d_ws, size_t ws_size,
                              hipStream_t stream) {
  const float* gctx = (const float*)d_in[1];
  const float* queries = (const float*)d_in[4];
  const float* image_tokens = (const float*)d_in[5];
  const float* W_in = (const float*)d_in[7];
  const float* W_ctx = (const float*)d_in[8];
  const float* ln_q_g = (const float*)d_in[9];
  const float* ln_q_b = (const float*)d_in[10];
  const float* Wq = (const float*)d_in[11];
  const float* ln_k_g = (const float*)d_in[12];
  const float* ln_k_b = (const float*)d_in[13];
  const float* Wk = (const float*)d_in[14];
  const float* ln_v_g = (const float*)d_in[15];
  const float* ln_v_b = (const float*)d_in[16];
  const float* Wv = (const float*)d_in[17];
  const float* Wo = (const float*)d_in[18];
  const float* norm_g = (const float*)d_in[19];
  const float* norm_b = (const float*)d_in[20];
  const float* W1 = (const float*)d_in[21];
  const float* W2 = (const float*)d_in[22];
  float* out = (float*)d_out;

  // ---- workspace arena (136 MiB, same layout as round 2) ----
  char* ws = (char*)d_ws;
  const size_t MB = 1024 * 1024;
  u16* w_in_b  = (u16*)(ws + 0 * MB);    // 4 MiB
  u16* w_ctx_b = (u16*)(ws + 4 * MB);
  u16* wq_b    = (u16*)(ws + 6 * MB);
  u16* wk_b    = (u16*)(ws + 8 * MB);
  u16* wv_b    = (u16*)(ws + 10 * MB);
  u16* wo_b    = (u16*)(ws + 12 * MB);
  u16* w1_b    = (u16*)(ws + 14 * MB);
  u16* w2_b    = (u16*)(ws + 16 * MB);
  char* regA = ws + 18 * MB;   // 64 MiB
  char* regB = regA + 64 * MB; // 36 MiB
  char* regC = regB + 36 * MB; // 18 MiB

  u16* acat = (u16*)regA;               // 16384 x 2048 bf16
  u16* pqln = (u16*)regA;               // 16384 x 1024 bf16 (acat dead)
  u16* qmat = (u16*)(regA + 32 * MB);   // 16384 x 1024 bf16
  u16* vln  = (u16*)regA;               // 9216 x 1024 bf16 (pqln dead)
  u16* aoh  = (u16*)regA;               // 16384 x 1024 bf16 (vln dead)
  u16* xmat = (u16*)(regA + 32 * MB);   // 16384 x 1024 bf16 (qmat dead)

  float* winp = (float*)regB;           // 9216 x 1024 f32
  u16* kmat = (u16*)regB;               // 9216 x 1024 bf16 (winp dead)
  u16* vmat = (u16*)(regB + 18 * MB);   // 9216 x 1024 bf16
  u16* gout = (u16*)regB;               // 16384 x 1024 bf16 (kmat/vmat dead)

  u16* gcb = (u16*)regC;                // 9216 x 1024 bf16
  u16* kln = (u16*)regC;                // 9216 x 1024 bf16 (gcb dead)

  float* pq = out;                      // f32 16384 x 1024, lives in d_out

  // ---- single batched convert for all weights + gctx ----
  Cvt9 jobs;
  const float* srcs[9] = {W_in, W_ctx, Wq, Wk, Wv, Wo, W1, W2, gctx};
  u16* dsts[9] = {w_in_b, w_ctx_b, wq_b, wk_b, wv_b, wo_b, w1_b, w2_b, gcb};
  long sizes[9] = {2048l * 1024, 1048576, 1048576, 1048576, 1048576,
                   1048576, 1048576, 1048576, 9216l * 1024};
  long cum = 0;
  for (int j = 0; j < 9; ++j) {
    jobs.s[j] = srcs[j];
    jobs.d[j] = dsts[j];
    jobs.cumv[j] = cum;
    cum += sizes[j] / 4;
  }
  jobs.cumv[9] = cum;
  convert_batch<<<dim3(2048), dim3(256), 0, stream>>>(jobs);
  build_acat<<<dim3(8192), dim3(256), 0, stream>>>(queries, image_tokens, acat);

  // 1D grids (XCD-swizzled inside the kernel): M=16384 -> 1024, M=9216 -> 576
  // pq = Acat @ W_in^T  (fp32 -> d_out)
  gemm_bt<1><<<dim3(1024), dim3(256), 0, stream>>>(acat, w_in_b, nullptr, pq,
                                                   nullptr, 16384, 1024, 2048);
  // ln_q(pq) -> bf16
  ln_rows<<<dim3(16384), dim3(256), 0, stream>>>(pq, ln_q_g, ln_q_b, pqln);
  // q = ln(pq) @ Wq^T  (bf16)
  gemm_bt<0><<<dim3(1024), dim3(256), 0, stream>>>(pqln, wq_b, qmat, nullptr,
                                                   nullptr, 16384, 1024, 1024);
  // winp = gctx_bf @ W_ctx^T  (fp32)
  gemm_bt<1><<<dim3(576), dim3(256), 0, stream>>>(gcb, w_ctx_b, nullptr, winp,
                                                  nullptr, 9216, 1024, 1024);
  // gather + ln_k / ln_v -> bf16
  ln_kv<<<dim3(9216), dim3(256), 0, stream>>>(winp, ln_k_g, ln_k_b, ln_v_g,
                                              ln_v_b, kln, vln);
  // k/v projections
  gemm_bt<0><<<dim3(576), dim3(256), 0, stream>>>(kln, wk_b, kmat, nullptr,
                                                  nullptr, 9216, 1024, 1024);
  gemm_bt<0><<<dim3(576), dim3(256), 0, stream>>>(vln, wv_b, vmat, nullptr,
                                                  nullptr, 9216, 1024, 1024);
  // attention
  attn_kernel<<<dim3(4096), dim3(256), 0, stream>>>(qmat, kmat, vmat, aoh);
  // y = ao @ Wo^T + pq  (fp32, in-place in d_out)
  gemm_bt<2><<<dim3(1024), dim3(256), 0, stream>>>(aoh, wo_b, nullptr, pq, pq,
                                                   16384, 1024, 1024);
  // x = ln(y) -> bf16
  ln_rows<<<dim3(16384), dim3(256), 0, stream>>>(pq, norm_g, norm_b, xmat);
  // h = gelu(x @ W1^T) -> bf16
  gemm_bt<3><<<dim3(1024), dim3(256), 0, stream>>>(xmat, w1_b, gout, nullptr,
                                                   nullptr, 16384, 1024, 1024);
  // out = h @ W2^T + image_tokens  (fp32 -> d_out)
  gemm_bt<2><<<dim3(1024), dim3(256), 0, stream>>>(gout, w2_b, nullptr, out,
                                                   image_tokens, 16384, 1024, 1024);
}